// Round 1
// baseline (494.136 us; speedup 1.0000x reference)
//
#include <hip/hip_runtime.h>
#include <hip/hip_bf16.h>
#include <stdint.h>

typedef __attribute__((ext_vector_type(8))) short short8;
typedef __attribute__((ext_vector_type(4))) float f32x4;

#define N_TOK  65536
#define DIM    256
#define NT     76          // 32-cluster tiles: 69 (L0) + 6 (L1) + 1 (L2)
#define TAU    0.05f

// padded layer map: L0 tiles [0,69) base 0 size 2197
//                   L1 tiles [69,75) base 2208 size 169
//                   L2 tile  75 base 2400 size 13

// workspace layout (bytes)
#define WS_FLAGCNT 0
#define WS_FLAGS   16
#define WS_NFLAGS  8192
#define WS_WNORM   32784                     // 16B aligned
#define WS_WHFRAG  65536
#define WS_WLFRAG  (WS_WHFRAG + NT*16384)    // each frag file: 76 tiles * 16KB

__device__ __forceinline__ unsigned short f2bf(float x) {
  unsigned u = __float_as_uint(x);
  u = (u + 0x7FFFu + ((u >> 16) & 1u)) >> 16;
  return (unsigned short)u;
}
__device__ __forceinline__ float bf2f(unsigned short h) {
  return __uint_as_float(((unsigned)h) << 16);
}

// ---------------- prep: pack W into MFMA A-frag order (hi/lo bf16) + wnorm ----
__global__ void prep_kernel(const float* __restrict__ w0, const float* __restrict__ w1,
                            const float* __restrict__ w2, unsigned char* __restrict__ ws) {
  const int t = blockIdx.x;
  const int tid = threadIdx.x;
  const float* wsrc; int basePad, csize;
  if (t < 69)      { wsrc = w0; basePad = 0;    csize = 2197; }
  else if (t < 75) { wsrc = w1; basePad = 2208; csize = 169;  }
  else             { wsrc = w2; basePad = 2400; csize = 13;   }
  short8* whf = (short8*)(ws + WS_WHFRAG);
  short8* wlf = (short8*)(ws + WS_WLFRAG);
#pragma unroll
  for (int r = 0; r < 2; ++r) {
    int q = r * 512 + tid;                  // frag slot within tile: sub*512 + s*64 + lane
    int lane = q & 63;
    int s = (q >> 6) & 7;
    int sub = q >> 9;
    int cit = sub * 16 + (lane & 15);
    int k = s * 32 + ((lane >> 4) & 3) * 8;
    int cl = t * 32 + cit - basePad;
    float xs[8];
    if (cl < csize) {
      const float4* p = (const float4*)(wsrc + (size_t)cl * DIM + k);
      float4 a = p[0], b = p[1];
      xs[0]=a.x; xs[1]=a.y; xs[2]=a.z; xs[3]=a.w; xs[4]=b.x; xs[5]=b.y; xs[6]=b.z; xs[7]=b.w;
    } else {
#pragma unroll
      for (int j = 0; j < 8; ++j) xs[j] = 0.0f;
    }
    short8 h, l;
#pragma unroll
    for (int j = 0; j < 8; ++j) {
      unsigned short hb = f2bf(xs[j]);
      float lr = xs[j] - bf2f(hb);
      h[j] = (short)hb;
      l[j] = (short)f2bf(lr);
    }
    whf[t * 1024 + q] = h;
    wlf[t * 1024 + q] = l;
  }
  if (tid < 32) {
    int cl = t * 32 + tid - basePad;
    float* wn = (float*)(ws + WS_WNORM);
    float v;
    if (cl < csize) {
      double acc = 0.0;
      for (int k = 0; k < DIM; ++k) { double x = wsrc[(size_t)cl * DIM + k]; acc += x * x; }
      v = (float)acc;
    } else v = __builtin_inff();
    wn[t * 32 + tid] = v;
  }
  if (t == 0 && tid == 0) *(int*)(ws + WS_FLAGCNT) = 0;
}

// ---------------- main: split-bf16 MFMA distances + per-token top2 + row write --
__global__ __launch_bounds__(512, 2) void argmin_kernel(
    const float* __restrict__ E, const float* __restrict__ w0, const float* __restrict__ w1,
    const float* __restrict__ w2, float* __restrict__ out, unsigned char* __restrict__ ws) {
  const int tid  = threadIdx.x;
  const int lane = tid & 63;
  const int wave = tid >> 6;
  const int col  = lane & 15;   // token within 16-tile
  const int grp  = lane >> 4;   // k-group / acc row group
  const int tokbase = blockIdx.x * 256 + wave * 32;

  // E fragments in registers: B-operand, lane holds E[tok = col][k = s*32 + grp*8 + j]
  short8 eh[2][8], el[2][8];
#pragma unroll
  for (int tt = 0; tt < 2; ++tt) {
    const float* ep = E + (size_t)(tokbase + tt * 16 + col) * DIM;
#pragma unroll
    for (int s = 0; s < 8; ++s) {
      const float4* p = (const float4*)(ep + s * 32 + grp * 8);
      float4 a = p[0], b = p[1];
      float xs[8] = {a.x, a.y, a.z, a.w, b.x, b.y, b.z, b.w};
      short8 h, l;
#pragma unroll
      for (int j = 0; j < 8; ++j) {
        unsigned short hb = f2bf(xs[j]);
        float lr = xs[j] - bf2f(hb);
        h[j] = (short)hb;
        l[j] = (short)f2bf(lr);
      }
      eh[tt][s] = h; el[tt][s] = l;
    }
  }

  const short8* whf = (const short8*)(ws + WS_WHFRAG);
  const short8* wlf = (const short8*)(ws + WS_WLFRAG);
  const float*  wn  = (const float*)(ws + WS_WNORM);

  __shared__ short8 wt[2][2][1024];   // [buf][hi/lo][sub*512+s*64+lane], 64KB

  // stage tile 0
  {
    int s0 = tid, s1 = tid + 512;
    wt[0][0][s0] = whf[s0]; wt[0][0][s1] = whf[s1];
    wt[0][1][s0] = wlf[s0]; wt[0][1][s1] = wlf[s1];
  }

  float v1[2] = {__builtin_inff(), __builtin_inff()};
  float v2[2] = {__builtin_inff(), __builtin_inff()};
  int   i1[2] = {0x7fffffff, 0x7fffffff};

  int cur = 0;
  for (int t = 0; t < NT; ++t) {
    __syncthreads();
    // prefetch next tile into regs (loads issue before MFMAs, stores after)
    short8 g0, g1, g2, g3;
    const bool pf = (t + 1 < NT);
    int s0 = tid, s1 = tid + 512;
    if (pf) {
      const short8* ph = whf + (t + 1) * 1024;
      const short8* pl = wlf + (t + 1) * 1024;
      g0 = ph[s0]; g1 = ph[s1]; g2 = pl[s0]; g3 = pl[s1];
    }
    // S = E·W^T for 32 clusters x 32 tokens, 3-pass split precision
    f32x4 acc[2][2];
#pragma unroll
    for (int sub = 0; sub < 2; ++sub)
#pragma unroll
      for (int tt = 0; tt < 2; ++tt)
        acc[sub][tt] = (f32x4){0.f, 0.f, 0.f, 0.f};
#pragma unroll
    for (int sub = 0; sub < 2; ++sub) {
#pragma unroll
      for (int s = 0; s < 8; ++s) {
        short8 Ah = wt[cur][0][(sub * 8 + s) * 64 + lane];
        short8 Al = wt[cur][1][(sub * 8 + s) * 64 + lane];
#pragma unroll
        for (int tt = 0; tt < 2; ++tt) {
          acc[sub][tt] = __builtin_amdgcn_mfma_f32_16x16x32_bf16(Ah, eh[tt][s], acc[sub][tt], 0, 0, 0);
          acc[sub][tt] = __builtin_amdgcn_mfma_f32_16x16x32_bf16(Ah, el[tt][s], acc[sub][tt], 0, 0, 0);
          acc[sub][tt] = __builtin_amdgcn_mfma_f32_16x16x32_bf16(Al, eh[tt][s], acc[sub][tt], 0, 0, 0);
        }
      }
    }
    int nb = cur ^ 1;
    if (pf) {
      wt[nb][0][s0] = g0; wt[nb][0][s1] = g1;
      wt[nb][1][s0] = g2; wt[nb][1][s1] = g3;
    }
    // epilogue: d = ||w||^2 - 2 S ; top2 update (first-min tie-break)
#pragma unroll
    for (int sub = 0; sub < 2; ++sub) {
      float4 w4 = *(const float4*)(wn + t * 32 + sub * 16 + grp * 4);
      float wr[4] = {w4.x, w4.y, w4.z, w4.w};
#pragma unroll
      for (int tt = 0; tt < 2; ++tt) {
#pragma unroll
        for (int r = 0; r < 4; ++r) {
          float d = wr[r] - 2.0f * acc[sub][tt][r];
          int c = t * 32 + sub * 16 + grp * 4 + r;
          bool lt = (d < v1[tt]) || (d == v1[tt] && c < i1[tt]);
          v2[tt] = fminf(v2[tt], lt ? v1[tt] : d);
          if (lt) { v1[tt] = d; i1[tt] = c; }
        }
      }
    }
    cur = nb;
    // layer finalize: cross-lane top2 merge, flag near-ties, write winning rows
    if (t == 68 || t == 74 || t == 75) {
      int L, basePad; const float* WL;
      if (t == 68)      { L = 0; basePad = 0;    WL = w0; }
      else if (t == 74) { L = 1; basePad = 2208; WL = w1; }
      else              { L = 2; basePad = 2400; WL = w2; }
#pragma unroll
      for (int tt = 0; tt < 2; ++tt) {
        float a1 = v1[tt]; int b1 = i1[tt]; float a2 = v2[tt];
#pragma unroll
        for (int off = 16; off <= 32; off <<= 1) {
          float o1 = __shfl_xor(a1, off, 64);
          int   oi = __shfl_xor(b1, off, 64);
          float o2 = __shfl_xor(a2, off, 64);
          bool take = (o1 < a1) || (o1 == a1 && oi < b1);
          float loser = take ? a1 : o1;
          if (take) { a1 = o1; b1 = oi; }
          a2 = fminf(loser, fminf(a2, o2));
        }
        int li = b1 - basePad;
        if (grp == 0) {
          if (a2 - a1 < TAU) {
            int token = tokbase + tt * 16 + col;
            int pos = atomicAdd((int*)(ws + WS_FLAGCNT), 1);
            if (pos < WS_NFLAGS) ((int*)(ws + WS_FLAGS))[pos] = (L << 16) | token;
          }
        }
#pragma unroll 1
        for (int r = 0; r < 16; ++r) {
          int ir = __shfl(li, r, 64);
          const float4* src = (const float4*)(WL + (size_t)ir * DIM);
          float4* dst = (float4*)(out + ((size_t)(L * N_TOK + tokbase + tt * 16 + r)) * DIM);
          dst[lane] = src[lane];
        }
        v1[tt] = __builtin_inff(); v2[tt] = __builtin_inff(); i1[tt] = 0x7fffffff;
      }
    }
  }
}

// ---------------- refine: exact fp64 rescan of flagged (token, layer) pairs ----
__global__ void refine_kernel(const float* __restrict__ E, const float* __restrict__ w0,
                              const float* __restrict__ w1, const float* __restrict__ w2,
                              float* __restrict__ out, unsigned char* __restrict__ ws) {
  __shared__ float esh[DIM];
  __shared__ double bv[256];
  __shared__ int    bix[256];
  const int tid = threadIdx.x;
  int cnt = *(const int*)(ws + WS_FLAGCNT);
  if (cnt > WS_NFLAGS) cnt = WS_NFLAGS;
  const int* flags = (const int*)(ws + WS_FLAGS);
  for (int f = blockIdx.x; f < cnt; f += gridDim.x) {
    int lin = flags[f];
    int L = lin >> 16, tok = lin & 0xffff;
    const float* WL; int csize;
    if (L == 0)      { WL = w0; csize = 2197; }
    else if (L == 1) { WL = w1; csize = 169; }
    else             { WL = w2; csize = 13; }
    esh[tid] = E[(size_t)tok * DIM + tid & 0xffffffff];  // tid < 256 == DIM
    __syncthreads();
    double best = 1e300; int bi = 0x7fffffff;
    for (int c = tid; c < csize; c += 256) {
      const float* wrow = WL + (size_t)c * DIM;
      double s = 0.0;
      for (int k = 0; k < DIM; ++k) {
        double dd = (double)wrow[k] - (double)esh[k];
        s += dd * dd;
      }
      if (s < best || (s == best && c < bi)) { best = s; bi = c; }
    }
    bv[tid] = best; bix[tid] = bi;
    __syncthreads();
    for (int off = 128; off > 0; off >>= 1) {
      if (tid < off) {
        double ov = bv[tid + off]; int oi = bix[tid + off];
        if (ov < bv[tid] || (ov == bv[tid] && oi < bix[tid])) { bv[tid] = ov; bix[tid] = oi; }
      }
      __syncthreads();
    }
    int bidx = bix[0];
    out[((size_t)(L * N_TOK + tok)) * DIM + tid] = WL[(size_t)bidx * DIM + tid];
    __syncthreads();
  }
}

extern "C" void kernel_launch(void* const* d_in, const int* in_sizes, int n_in,
                              void* d_out, int out_size, void* d_ws, size_t ws_size,
                              hipStream_t stream) {
  const float* E  = (const float*)d_in[0];
  const float* w0 = (const float*)d_in[1];
  const float* w1 = (const float*)d_in[2];
  const float* w2 = (const float*)d_in[3];
  float* out = (float*)d_out;
  unsigned char* ws = (unsigned char*)d_ws;

  hipLaunchKernelGGL(prep_kernel,   dim3(NT),  dim3(512), 0, stream, w0, w1, w2, ws);
  hipLaunchKernelGGL(argmin_kernel, dim3(256), dim3(512), 0, stream, E, w0, w1, w2, out, ws);
  hipLaunchKernelGGL(refine_kernel, dim3(128), dim3(256), 0, stream, E, w0, w1, w2, out, ws);
}

// Round 3
// 418.834 us; speedup vs baseline: 1.1798x; 1.1798x over previous
//
#include <hip/hip_runtime.h>
#include <hip/hip_bf16.h>
#include <stdint.h>

typedef __attribute__((ext_vector_type(8))) _Float16 half8;
typedef __attribute__((ext_vector_type(4))) float f32x4;

#define N_TOK  65536
#define DIM    256
#define NT     76          // 32-cluster tiles: 69 (L0) + 6 (L1) + 1 (L2)
#define TAU    0.08f

// padded layer map: L0 tiles [0,69) base 0 size 2197
//                   L1 tiles [69,75) base 2208 size 169
//                   L2 tile  75 base 2400 size 13

// workspace layout (bytes)
#define WS_FLAGCNT 0
#define WS_FLAGS   64
#define WS_NFLAGS  16384
#define WS_WNORM   (64 + WS_NFLAGS*4)        // 65600, 16B aligned
#define WS_WHFRAG  131072                    // fp16 hi frags: 76 tiles * 16KB

// ---------------- prep: pack W into MFMA A-frag order (fp16 hi) + fp64 wnorm --
__global__ void prep_kernel(const float* __restrict__ w0, const float* __restrict__ w1,
                            const float* __restrict__ w2, unsigned char* __restrict__ ws) {
  const int t = blockIdx.x;
  const int tid = threadIdx.x;           // 256 threads
  const float* wsrc; int basePad, csize;
  if (t < 69)      { wsrc = w0; basePad = 0;    csize = 2197; }
  else if (t < 75) { wsrc = w1; basePad = 2208; csize = 169;  }
  else             { wsrc = w2; basePad = 2400; csize = 13;   }
  half8* whf = (half8*)(ws + WS_WHFRAG);
#pragma unroll
  for (int r = 0; r < 4; ++r) {
    int q = r * 256 + tid;               // frag slot within tile: sub*512 + s*64 + lane
    int lane = q & 63;
    int s = (q >> 6) & 7;
    int sub = q >> 9;
    int cit = sub * 16 + (lane & 15);
    int k = s * 32 + ((lane >> 4) & 3) * 8;
    int cl = t * 32 + cit - basePad;
    float xs[8];
    if (cl < csize) {
      const float4* p = (const float4*)(wsrc + (size_t)cl * DIM + k);
      float4 a = p[0], b = p[1];
      xs[0]=a.x; xs[1]=a.y; xs[2]=a.z; xs[3]=a.w; xs[4]=b.x; xs[5]=b.y; xs[6]=b.z; xs[7]=b.w;
    } else {
#pragma unroll
      for (int j = 0; j < 8; ++j) xs[j] = 0.0f;
    }
    half8 h;
#pragma unroll
    for (int j = 0; j < 8; ++j) h[j] = (_Float16)xs[j];
    whf[(size_t)t * 1024 + q] = h;
  }
  // wnorm: 8 threads per cluster, fp64, shuffle-reduce
  {
    int gid = tid >> 3, j = tid & 7;     // gid 0..31
    int cl = t * 32 + gid - basePad;
    double acc = 0.0;
    if (cl >= 0 && cl < csize) {
      const float* row = wsrc + (size_t)cl * DIM + j * 32;
#pragma unroll
      for (int k = 0; k < 32; ++k) { double x = row[k]; acc += x * x; }
    }
    acc += __shfl_xor(acc, 1, 64);
    acc += __shfl_xor(acc, 2, 64);
    acc += __shfl_xor(acc, 4, 64);
    if (j == 0) {
      float* wn = (float*)(ws + WS_WNORM);
      wn[t * 32 + gid] = (cl >= 0 && cl < csize) ? (float)acc : __builtin_inff();
    }
  }
  if (t == 0 && tid == 0) *(int*)(ws + WS_FLAGCNT) = 0;
}

// ---------------- main: 2-pass fp16 MFMA distances + per-token top2 + row write --
__global__ __launch_bounds__(256, 2) void argmin_kernel(
    const float* __restrict__ E, const float* __restrict__ w0, const float* __restrict__ w1,
    const float* __restrict__ w2, float* __restrict__ out, unsigned char* __restrict__ ws) {
  const int tid  = threadIdx.x;
  const int lane = tid & 63;
  const int wave = tid >> 6;     // 0..3
  const int col  = lane & 15;    // token within 16-tile
  const int grp  = lane >> 4;    // k-group / acc row group
  const int tokbase = blockIdx.x * 128 + wave * 32;

  // E fragments in registers (B-operand): lane holds E[tok=col][k = s*32 + grp*8 + j]
  half8 eh[2][8], el[2][8];
#pragma unroll
  for (int tt = 0; tt < 2; ++tt) {
    const float* ep = E + (size_t)(tokbase + tt * 16 + col) * DIM;
#pragma unroll
    for (int s = 0; s < 8; ++s) {
      const float4* p = (const float4*)(ep + s * 32 + grp * 8);
      float4 a = p[0], b = p[1];
      float xs[8] = {a.x, a.y, a.z, a.w, b.x, b.y, b.z, b.w};
      half8 h, l;
#pragma unroll
      for (int j = 0; j < 8; ++j) {
        _Float16 hv = (_Float16)xs[j];
        h[j] = hv;
        l[j] = (_Float16)(xs[j] - (float)hv);
      }
      eh[tt][s] = h; el[tt][s] = l;
    }
  }

  const half8* whf = (const half8*)(ws + WS_WHFRAG);
  const float* wn  = (const float*)(ws + WS_WNORM);

  __shared__ half8 wt[2][1024];   // [buf][sub*512+s*64+lane], 32KB total

  // stage tile 0 (4 slots per thread)
#pragma unroll
  for (int r = 0; r < 4; ++r) wt[0][r * 256 + tid] = whf[r * 256 + tid];

  float v1[2] = {__builtin_inff(), __builtin_inff()};
  float v2[2] = {__builtin_inff(), __builtin_inff()};
  int   i1[2] = {0x7fffffff, 0x7fffffff};

  int cur = 0;
#pragma unroll 1
  for (int t = 0; t < NT; ++t) {
    __syncthreads();
    // prefetch next tile into regs (loads issue before MFMAs, LDS stores after)
    half8 g0, g1, g2, g3;
    const bool pf = (t + 1 < NT);
    if (pf) {
      const half8* ph = whf + (size_t)(t + 1) * 1024;
      g0 = ph[tid]; g1 = ph[tid + 256]; g2 = ph[tid + 512]; g3 = ph[tid + 768];
    }
    // S = E·W^T for 32 clusters x 32 tokens, 2-pass fp16 (W hi-only)
    f32x4 acc[2][2];
#pragma unroll
    for (int sub = 0; sub < 2; ++sub)
#pragma unroll
      for (int tt = 0; tt < 2; ++tt)
        acc[sub][tt] = (f32x4){0.f, 0.f, 0.f, 0.f};
#pragma unroll
    for (int sub = 0; sub < 2; ++sub) {
#pragma unroll
      for (int s = 0; s < 8; ++s) {
        half8 Ah = wt[cur][(sub * 8 + s) * 64 + lane];
#pragma unroll
        for (int tt = 0; tt < 2; ++tt) {
          acc[sub][tt] = __builtin_amdgcn_mfma_f32_16x16x32_f16(Ah, eh[tt][s], acc[sub][tt], 0, 0, 0);
          acc[sub][tt] = __builtin_amdgcn_mfma_f32_16x16x32_f16(Ah, el[tt][s], acc[sub][tt], 0, 0, 0);
        }
      }
    }
    int nb = cur ^ 1;
    if (pf) {
      wt[nb][tid] = g0; wt[nb][tid + 256] = g1; wt[nb][tid + 512] = g2; wt[nb][tid + 768] = g3;
    }
    // epilogue: d = ||w||^2 - 2 S ; top2 update (first-min tie-break)
#pragma unroll
    for (int sub = 0; sub < 2; ++sub) {
      float4 w4 = *(const float4*)(wn + t * 32 + sub * 16 + grp * 4);
      float wr[4] = {w4.x, w4.y, w4.z, w4.w};
#pragma unroll
      for (int tt = 0; tt < 2; ++tt) {
#pragma unroll
        for (int r = 0; r < 4; ++r) {
          float d = wr[r] - 2.0f * acc[sub][tt][r];
          int c = t * 32 + sub * 16 + grp * 4 + r;
          bool lt = (d < v1[tt]) || (d == v1[tt] && c < i1[tt]);
          v2[tt] = fminf(v2[tt], lt ? v1[tt] : d);
          if (lt) { v1[tt] = d; i1[tt] = c; }
        }
      }
    }
    cur = nb;
    // layer finalize: cross-lane top2 merge, flag near-ties, write winning rows
    if (t == 68 || t == 74 || t == 75) {
      int L, basePad; const float* WL;
      if (t == 68)      { L = 0; basePad = 0;    WL = w0; }
      else if (t == 74) { L = 1; basePad = 2208; WL = w1; }
      else              { L = 2; basePad = 2400; WL = w2; }
#pragma unroll
      for (int tt = 0; tt < 2; ++tt) {
        float a1 = v1[tt]; int b1 = i1[tt]; float a2 = v2[tt];
#pragma unroll
        for (int off = 16; off <= 32; off <<= 1) {
          float o1 = __shfl_xor(a1, off, 64);
          int   oi = __shfl_xor(b1, off, 64);
          float o2 = __shfl_xor(a2, off, 64);
          bool take = (o1 < a1) || (o1 == a1 && oi < b1);
          float loser = take ? a1 : o1;
          if (take) { a1 = o1; b1 = oi; }
          a2 = fminf(loser, fminf(a2, o2));
        }
        int li = b1 - basePad;
        if (grp == 0) {
          if (a2 - a1 < TAU) {
            int token = tokbase + tt * 16 + col;
            int pos = atomicAdd((int*)(ws + WS_FLAGCNT), 1);
            if (pos < WS_NFLAGS) ((int*)(ws + WS_FLAGS))[pos] = (L << 16) | token;
          }
        }
#pragma unroll 1
        for (int r = 0; r < 16; ++r) {
          int ir = __shfl(li, r, 64);
          const f32x4* src = (const f32x4*)(WL + (size_t)ir * DIM);
          f32x4* dst = (f32x4*)(out + ((size_t)(L * N_TOK + tokbase + tt * 16 + r)) * DIM);
          __builtin_nontemporal_store(src[lane], &dst[lane]);
        }
        v1[tt] = __builtin_inff(); v2[tt] = __builtin_inff(); i1[tt] = 0x7fffffff;
      }
    }
  }
}

// ---------------- refine: exact fp64 rescan of flagged (token, layer) pairs ----
__global__ void refine_kernel(const float* __restrict__ E, const float* __restrict__ w0,
                              const float* __restrict__ w1, const float* __restrict__ w2,
                              float* __restrict__ out, unsigned char* __restrict__ ws) {
  __shared__ float esh[DIM];
  __shared__ double bv[256];
  __shared__ int    bix[256];
  const int tid = threadIdx.x;
  int cnt = *(const int*)(ws + WS_FLAGCNT);
  if (cnt > WS_NFLAGS) cnt = WS_NFLAGS;
  const int* flags = (const int*)(ws + WS_FLAGS);
  for (int f = blockIdx.x; f < cnt; f += gridDim.x) {
    int lin = flags[f];
    int L = lin >> 16, tok = lin & 0xffff;
    const float* WL; int csize;
    if (L == 0)      { WL = w0; csize = 2197; }
    else if (L == 1) { WL = w1; csize = 169; }
    else             { WL = w2; csize = 13; }
    esh[tid] = E[(size_t)tok * DIM + tid];   // tid < 256 == DIM
    __syncthreads();
    double best = 1e300; int bi = 0x7fffffff;
    for (int c = tid; c < csize; c += 256) {
      const float* wrow = WL + (size_t)c * DIM;
      double s = 0.0;
      for (int k = 0; k < DIM; ++k) {
        double dd = (double)wrow[k] - (double)esh[k];
        s += dd * dd;
      }
      if (s < best || (s == best && c < bi)) { best = s; bi = c; }
    }
    bv[tid] = best; bix[tid] = bi;
    __syncthreads();
    for (int off = 128; off > 0; off >>= 1) {
      if (tid < off) {
        double ov = bv[tid + off]; int oi = bix[tid + off];
        if (ov < bv[tid] || (ov == bv[tid] && oi < bix[tid])) { bv[tid] = ov; bix[tid] = oi; }
      }
      __syncthreads();
    }
    int bidx = bix[0];
    out[((size_t)(L * N_TOK + tok)) * DIM + tid] = WL[(size_t)bidx * DIM + tid];
    __syncthreads();
  }
}

extern "C" void kernel_launch(void* const* d_in, const int* in_sizes, int n_in,
                              void* d_out, int out_size, void* d_ws, size_t ws_size,
                              hipStream_t stream) {
  const float* E  = (const float*)d_in[0];
  const float* w0 = (const float*)d_in[1];
  const float* w1 = (const float*)d_in[2];
  const float* w2 = (const float*)d_in[3];
  float* out = (float*)d_out;
  unsigned char* ws = (unsigned char*)d_ws;

  hipLaunchKernelGGL(prep_kernel,   dim3(NT),  dim3(256), 0, stream, w0, w1, w2, ws);
  hipLaunchKernelGGL(argmin_kernel, dim3(512), dim3(256), 0, stream, E, w0, w1, w2, out, ws);
  hipLaunchKernelGGL(refine_kernel, dim3(256), dim3(256), 0, stream, E, w0, w1, w2, out, ws);
}

// Round 4
// 305.523 us; speedup vs baseline: 1.6173x; 1.3709x over previous
//
#include <hip/hip_runtime.h>
#include <hip/hip_bf16.h>
#include <stdint.h>

typedef __attribute__((ext_vector_type(8))) _Float16 half8;
typedef __attribute__((ext_vector_type(4))) float f32x4;

#define N_TOK  65536
#define DIM    256
#define NT     76          // 32-cluster tiles: 69 (L0) + 6 (L1) + 1 (L2)
#define TAU    0.08f

// padded layer map: L0 tiles [0,69) base 0 size 2197
//                   L1 tiles [69,75) base 2208 size 169
//                   L2 tile  75 base 2400 size 13

// workspace layout (bytes)
#define WS_FLAGCNT 0
#define WS_FLAGS   64
#define WS_NFLAGS  16384
#define WS_WNORM   (64 + WS_NFLAGS*4)        // 65600, 16B aligned
#define WS_WHFRAG  131072                    // fp16 hi frags: 76 tiles * 16KB

// ---------------- prep: pack W into MFMA A-frag order (fp16 hi) + fp64 wnorm --
__global__ void prep_kernel(const float* __restrict__ w0, const float* __restrict__ w1,
                            const float* __restrict__ w2, unsigned char* __restrict__ ws) {
  const int t = blockIdx.x;
  const int tid = threadIdx.x;           // 256 threads
  const float* wsrc; int basePad, csize;
  if (t < 69)      { wsrc = w0; basePad = 0;    csize = 2197; }
  else if (t < 75) { wsrc = w1; basePad = 2208; csize = 169;  }
  else             { wsrc = w2; basePad = 2400; csize = 13;   }
  half8* whf = (half8*)(ws + WS_WHFRAG);
#pragma unroll
  for (int r = 0; r < 4; ++r) {
    int q = r * 256 + tid;               // frag slot within tile: sub*512 + s*64 + lane
    int lane = q & 63;
    int s = (q >> 6) & 7;
    int sub = q >> 9;
    int cit = sub * 16 + (lane & 15);
    int k = s * 32 + ((lane >> 4) & 3) * 8;
    int cl = t * 32 + cit - basePad;
    float xs[8];
    if (cl < csize) {
      const float4* p = (const float4*)(wsrc + (size_t)cl * DIM + k);
      float4 a = p[0], b = p[1];
      xs[0]=a.x; xs[1]=a.y; xs[2]=a.z; xs[3]=a.w; xs[4]=b.x; xs[5]=b.y; xs[6]=b.z; xs[7]=b.w;
    } else {
#pragma unroll
      for (int j = 0; j < 8; ++j) xs[j] = 0.0f;
    }
    half8 h;
#pragma unroll
    for (int j = 0; j < 8; ++j) h[j] = (_Float16)xs[j];
    whf[(size_t)t * 1024 + q] = h;
  }
  // wnorm: 8 threads per cluster, fp64, shuffle-reduce
  {
    int gid = tid >> 3, j = tid & 7;     // gid 0..31
    int cl = t * 32 + gid - basePad;
    double acc = 0.0;
    if (cl >= 0 && cl < csize) {
      const float* row = wsrc + (size_t)cl * DIM + j * 32;
#pragma unroll
      for (int k = 0; k < 32; ++k) { double x = row[k]; acc += x * x; }
    }
    acc += __shfl_xor(acc, 1, 64);
    acc += __shfl_xor(acc, 2, 64);
    acc += __shfl_xor(acc, 4, 64);
    if (j == 0) {
      float* wn = (float*)(ws + WS_WNORM);
      wn[t * 32 + gid] = (cl >= 0 && cl < csize) ? (float)acc : __builtin_inff();
    }
  }
  if (t == 0 && tid == 0) *(int*)(ws + WS_FLAGCNT) = 0;
}

// ------- main: 2-pass fp16 MFMA distances, 16 tok/wave, 4 blocks/CU ----------
__global__ __launch_bounds__(256, 4) void argmin_kernel(
    const float* __restrict__ E, const float* __restrict__ w0, const float* __restrict__ w1,
    const float* __restrict__ w2, float* __restrict__ out, unsigned char* __restrict__ ws) {
  const int tid  = threadIdx.x;
  const int lane = tid & 63;
  const int wave = tid >> 6;     // 0..3
  const int col  = lane & 15;    // token within 16-tile
  const int grp  = lane >> 4;    // k-group / acc row group
  const int tokbase = blockIdx.x * 64 + wave * 16;

  // E fragments in registers (B-operand): lane holds E[tok=col][k = s*32 + grp*8 + j]
  half8 eh[8], el[8];
  {
    const float* ep = E + (size_t)(tokbase + col) * DIM;
#pragma unroll
    for (int s = 0; s < 8; ++s) {
      const float4* p = (const float4*)(ep + s * 32 + grp * 8);
      float4 a = p[0], b = p[1];
      float xs[8] = {a.x, a.y, a.z, a.w, b.x, b.y, b.z, b.w};
      half8 h, l;
#pragma unroll
      for (int j = 0; j < 8; ++j) {
        _Float16 hv = (_Float16)xs[j];
        h[j] = hv;
        l[j] = (_Float16)(xs[j] - (float)hv);
      }
      eh[s] = h; el[s] = l;
    }
  }

  const half8* whf = (const half8*)(ws + WS_WHFRAG);
  const float* wn  = (const float*)(ws + WS_WNORM);

  __shared__ half8 wt[2][1024];   // [buf][sub*512+s*64+lane], 32KB total

  // stage tile 0 (4 slots per thread)
#pragma unroll
  for (int r = 0; r < 4; ++r) wt[0][r * 256 + tid] = whf[r * 256 + tid];

  float v1 = __builtin_inff();
  float v2 = __builtin_inff();
  int   i1 = 0x7fffffff;

  int cur = 0;
#pragma unroll 1
  for (int t = 0; t < NT; ++t) {
    __syncthreads();
    // prefetch next tile into regs (loads issue before MFMAs, LDS stores after)
    half8 g0, g1, g2, g3;
    const bool pf = (t + 1 < NT);
    if (pf) {
      const half8* ph = whf + (size_t)(t + 1) * 1024;
      g0 = ph[tid]; g1 = ph[tid + 256]; g2 = ph[tid + 512]; g3 = ph[tid + 768];
    }
    // S = E·W^T for 32 clusters x 16 tokens, 2-pass fp16 (W hi-only)
    f32x4 acc[2];
#pragma unroll
    for (int sub = 0; sub < 2; ++sub) acc[sub] = (f32x4){0.f, 0.f, 0.f, 0.f};
#pragma unroll
    for (int sub = 0; sub < 2; ++sub) {
#pragma unroll
      for (int s = 0; s < 8; ++s) {
        half8 Ah = wt[cur][(sub * 8 + s) * 64 + lane];
        acc[sub] = __builtin_amdgcn_mfma_f32_16x16x32_f16(Ah, eh[s], acc[sub], 0, 0, 0);
        acc[sub] = __builtin_amdgcn_mfma_f32_16x16x32_f16(Ah, el[s], acc[sub], 0, 0, 0);
      }
    }
    int nb = cur ^ 1;
    if (pf) {
      wt[nb][tid] = g0; wt[nb][tid + 256] = g1; wt[nb][tid + 512] = g2; wt[nb][tid + 768] = g3;
    }
    // epilogue: d = ||w||^2 - 2 S ; top2 update (first-min tie-break)
#pragma unroll
    for (int sub = 0; sub < 2; ++sub) {
      float4 w4 = *(const float4*)(wn + t * 32 + sub * 16 + grp * 4);
      float wr[4] = {w4.x, w4.y, w4.z, w4.w};
#pragma unroll
      for (int r = 0; r < 4; ++r) {
        float d = wr[r] - 2.0f * acc[sub][r];
        int c = t * 32 + sub * 16 + grp * 4 + r;
        bool lt = (d < v1) || (d == v1 && c < i1);
        v2 = fminf(v2, lt ? v1 : d);
        if (lt) { v1 = d; i1 = c; }
      }
    }
    cur = nb;
    // layer finalize: cross-lane top2 merge, flag near-ties, write winning rows
    if (t == 68 || t == 74 || t == 75) {
      int L, basePad; const float* WL;
      if (t == 68)      { L = 0; basePad = 0;    WL = w0; }
      else if (t == 74) { L = 1; basePad = 2208; WL = w1; }
      else              { L = 2; basePad = 2400; WL = w2; }
      float a1 = v1; int b1 = i1; float a2 = v2;
#pragma unroll
      for (int off = 16; off <= 32; off <<= 1) {
        float o1 = __shfl_xor(a1, off, 64);
        int   oi = __shfl_xor(b1, off, 64);
        float o2 = __shfl_xor(a2, off, 64);
        bool take = (o1 < a1) || (o1 == a1 && oi < b1);
        float loser = take ? a1 : o1;
        if (take) { a1 = o1; b1 = oi; }
        a2 = fminf(loser, fminf(a2, o2));
      }
      int li = b1 - basePad;
      if (grp == 0) {
        if (a2 - a1 < TAU) {
          int token = tokbase + col;
          int pos = atomicAdd((int*)(ws + WS_FLAGCNT), 1);
          if (pos < WS_NFLAGS) ((int*)(ws + WS_FLAGS))[pos] = (L << 16) | token;
        }
      }
#pragma unroll 1
      for (int r = 0; r < 16; ++r) {
        int ir = __shfl(li, r, 64);
        const f32x4* src = (const f32x4*)(WL + (size_t)ir * DIM);
        f32x4* dst = (f32x4*)(out + ((size_t)(L * N_TOK + tokbase + r)) * DIM);
        __builtin_nontemporal_store(src[lane], &dst[lane]);
      }
      v1 = __builtin_inff(); v2 = __builtin_inff(); i1 = 0x7fffffff;
    }
  }
}

// ------- refine: exact fp64 rescan, 16-lane cluster groups, coalesced --------
__global__ __launch_bounds__(256) void refine_kernel(
    const float* __restrict__ E, const float* __restrict__ w0,
    const float* __restrict__ w1, const float* __restrict__ w2,
    float* __restrict__ out, unsigned char* __restrict__ ws) {
  __shared__ float esh[DIM];
  __shared__ double wbv[4];
  __shared__ int    wbi[4];
  __shared__ int    sbi;
  const int tid  = threadIdx.x;
  const int lane = tid & 63;
  const int wave = tid >> 6;
  const int g    = tid >> 4;    // 0..15 cluster group
  const int sl   = tid & 15;    // sub-lane within group
  int cnt = *(const int*)(ws + WS_FLAGCNT);
  if (cnt > WS_NFLAGS) cnt = WS_NFLAGS;
  const int* flags = (const int*)(ws + WS_FLAGS);
  for (int f = blockIdx.x; f < cnt; f += gridDim.x) {
    int lin = flags[f];
    int L = lin >> 16, tok = lin & 0xffff;
    const float* WL; int csize;
    if (L == 0)      { WL = w0; csize = 2197; }
    else if (L == 1) { WL = w1; csize = 169; }
    else             { WL = w2; csize = 13; }
    __syncthreads();                         // protect esh/wbv reuse
    esh[tid] = E[(size_t)tok * DIM + tid];   // tid < 256 == DIM
    __syncthreads();
    double best = 1e300; int bi = 0x7fffffff;
    const float4* er = (const float4*)esh;
    for (int c = g; c < csize; c += 16) {
      const float4* row = (const float4*)(WL + (size_t)c * DIM);
      double s0 = 0.0, s1 = 0.0, s2 = 0.0, s3 = 0.0;
#pragma unroll
      for (int p = 0; p < 4; ++p) {
        float4 wv = row[p * 16 + sl];
        float4 ev = er [p * 16 + sl];
        double d0 = (double)wv.x - (double)ev.x;
        double d1 = (double)wv.y - (double)ev.y;
        double d2 = (double)wv.z - (double)ev.z;
        double d3 = (double)wv.w - (double)ev.w;
        s0 += d0 * d0; s1 += d1 * d1; s2 += d2 * d2; s3 += d3 * d3;
      }
      double s = (s0 + s1) + (s2 + s3);
      s += __shfl_xor(s, 1, 64);
      s += __shfl_xor(s, 2, 64);
      s += __shfl_xor(s, 4, 64);
      s += __shfl_xor(s, 8, 64);
      if (s < best || (s == best && c < bi)) { best = s; bi = c; }
    }
    // merge 4 groups within the wave
    {
      double ob = __shfl_xor(best, 16, 64); int oi = __shfl_xor(bi, 16, 64);
      if (ob < best || (ob == best && oi < bi)) { best = ob; bi = oi; }
      ob = __shfl_xor(best, 32, 64); oi = __shfl_xor(bi, 32, 64);
      if (ob < best || (ob == best && oi < bi)) { best = ob; bi = oi; }
    }
    if (lane == 0) { wbv[wave] = best; wbi[wave] = bi; }
    __syncthreads();
    if (tid == 0) {
      double b = wbv[0]; int x = wbi[0];
#pragma unroll
      for (int w = 1; w < 4; ++w)
        if (wbv[w] < b || (wbv[w] == b && wbi[w] < x)) { b = wbv[w]; x = wbi[w]; }
      sbi = x;
    }
    __syncthreads();
    int bidx = sbi;
    out[((size_t)(L * N_TOK + tok)) * DIM + tid] = WL[(size_t)bidx * DIM + tid];
  }
}

extern "C" void kernel_launch(void* const* d_in, const int* in_sizes, int n_in,
                              void* d_out, int out_size, void* d_ws, size_t ws_size,
                              hipStream_t stream) {
  const float* E  = (const float*)d_in[0];
  const float* w0 = (const float*)d_in[1];
  const float* w1 = (const float*)d_in[2];
  const float* w2 = (const float*)d_in[3];
  float* out = (float*)d_out;
  unsigned char* ws = (unsigned char*)d_ws;

  hipLaunchKernelGGL(prep_kernel,   dim3(NT),   dim3(256), 0, stream, w0, w1, w2, ws);
  hipLaunchKernelGGL(argmin_kernel, dim3(1024), dim3(256), 0, stream, E, w0, w1, w2, out, ws);
  hipLaunchKernelGGL(refine_kernel, dim3(1024), dim3(256), 0, stream, E, w0, w1, w2, out, ws);
}

// Round 5
// 276.720 us; speedup vs baseline: 1.7857x; 1.1041x over previous
//
#include <hip/hip_runtime.h>
#include <hip/hip_bf16.h>
#include <stdint.h>

typedef __attribute__((ext_vector_type(8))) _Float16 half8;
typedef __attribute__((ext_vector_type(4))) float f32x4;
typedef __attribute__((ext_vector_type(16))) float f32x16;

#define N_TOK  65536
#define DIM    256
#define NT     76          // 32-cluster tiles: 69 (L0) + 6 (L1) + 1 (L2)
#define TAU    0.12f

// padded layer map: L0 tiles [0,69) base 0 size 2197
//                   L1 tiles [69,75) base 2208 size 169
//                   L2 tile  75 base 2400 size 13

// workspace layout (bytes)
#define WS_FLAGCNT 0
#define WS_FLAGS   64
#define WS_NFLAGS  16384
#define WS_WNORM   (64 + WS_NFLAGS*4)        // 65600, 16B aligned
#define WS_WHFRAG  131072                    // fp16 hi frags: 76 tiles * 16KB

// -------- prep: pack W into 32x32x16 MFMA A-frag order (fp16 hi) + fp64 wnorm --
// frag slot q = s*64 + l  (s = K-step 0..15, l = lane): cluster = l&31,
// k = s*16 + (l>>5)*8 + j  (8 contiguous fp16 per lane)
__global__ void prep_kernel(const float* __restrict__ w0, const float* __restrict__ w1,
                            const float* __restrict__ w2, unsigned char* __restrict__ ws) {
  const int t = blockIdx.x;
  const int tid = threadIdx.x;           // 256 threads
  const float* wsrc; int basePad, csize;
  if (t < 69)      { wsrc = w0; basePad = 0;    csize = 2197; }
  else if (t < 75) { wsrc = w1; basePad = 2208; csize = 169;  }
  else             { wsrc = w2; basePad = 2400; csize = 13;   }
  half8* whf = (half8*)(ws + WS_WHFRAG);
#pragma unroll
  for (int r = 0; r < 4; ++r) {
    int q = r * 256 + tid;               // frag slot within tile
    int l = q & 63;
    int s = q >> 6;                      // 0..15
    int cit = l & 31;
    int k = s * 16 + (l >> 5) * 8;
    int cl = t * 32 + cit - basePad;
    float xs[8];
    if (cl < csize) {
      const float4* p = (const float4*)(wsrc + (size_t)cl * DIM + k);
      float4 a = p[0], b = p[1];
      xs[0]=a.x; xs[1]=a.y; xs[2]=a.z; xs[3]=a.w; xs[4]=b.x; xs[5]=b.y; xs[6]=b.z; xs[7]=b.w;
    } else {
#pragma unroll
      for (int j = 0; j < 8; ++j) xs[j] = 0.0f;
    }
    half8 h;
#pragma unroll
    for (int j = 0; j < 8; ++j) h[j] = (_Float16)xs[j];
    whf[(size_t)t * 1024 + q] = h;
  }
  // wnorm: 8 threads per cluster, fp64, shuffle-reduce
  {
    int gid = tid >> 3, j = tid & 7;     // gid 0..31
    int cl = t * 32 + gid - basePad;
    double acc = 0.0;
    if (cl >= 0 && cl < csize) {
      const float* row = wsrc + (size_t)cl * DIM + j * 32;
#pragma unroll
      for (int k = 0; k < 32; ++k) { double x = row[k]; acc += x * x; }
    }
    acc += __shfl_xor(acc, 1, 64);
    acc += __shfl_xor(acc, 2, 64);
    acc += __shfl_xor(acc, 4, 64);
    if (j == 0) {
      float* wn = (float*)(ws + WS_WNORM);
      wn[t * 32 + gid] = (cl >= 0 && cl < csize) ? (float)acc : __builtin_inff();
    }
  }
  if (t == 0 && tid == 0) *(int*)(ws + WS_FLAGCNT) = 0;
}

// -------- main: 1-pass fp16 32x32x16 MFMA, 32 tok/wave, 2-wave blocks ---------
__global__ __launch_bounds__(128, 2) void argmin_kernel(
    const float* __restrict__ E, const float* __restrict__ w0, const float* __restrict__ w1,
    const float* __restrict__ w2, float* __restrict__ out, unsigned char* __restrict__ ws) {
  const int tid   = threadIdx.x;
  const int lane  = tid & 63;
  const int wave  = tid >> 6;    // 0..1
  const int col   = lane & 31;   // token within 32-tile
  const int khalf = lane >> 5;   // 0/1 (k sub-block / C-row offset)
  const int tokbase = blockIdx.x * 64 + wave * 32;

  // E fragments (B-operand): lane holds E[tok=col][k = s*16 + khalf*8 + j]
  half8 eh[16];
  {
    const float* ep = E + (size_t)(tokbase + col) * DIM;
#pragma unroll
    for (int s = 0; s < 16; ++s) {
      const float4* p = (const float4*)(ep + s * 16 + khalf * 8);
      float4 a = p[0], b = p[1];
      float xs[8] = {a.x, a.y, a.z, a.w, b.x, b.y, b.z, b.w};
      half8 h;
#pragma unroll
      for (int j = 0; j < 8; ++j) h[j] = (_Float16)xs[j];
      eh[s] = h;
    }
  }

  const half8* whf = (const half8*)(ws + WS_WHFRAG);
  const float* wn  = (const float*)(ws + WS_WNORM);

  __shared__ half8 wt[2][1024];   // [buf][s*64+lane], 32KB total

  // stage tile 0 (8 slots per thread)
#pragma unroll
  for (int r = 0; r < 8; ++r) wt[0][r * 128 + tid] = whf[r * 128 + tid];

  float v1 = __builtin_inff();
  float v2 = __builtin_inff();
  int   i1 = 0x7fffffff;

  int cur = 0;
#pragma unroll 1
  for (int t = 0; t < NT; ++t) {
    __syncthreads();
    // prefetch next tile into regs (loads issue before MFMAs, LDS stores after)
    half8 g[8];
    const bool pf = (t + 1 < NT);
    if (pf) {
      const half8* ph = whf + (size_t)(t + 1) * 1024;
#pragma unroll
      for (int r = 0; r < 8; ++r) g[r] = ph[r * 128 + tid];
    }
    // S = E·W^T for 32 clusters x 32 tokens, hi-only fp16
    f32x16 acc = (f32x16){0.f,0.f,0.f,0.f,0.f,0.f,0.f,0.f,0.f,0.f,0.f,0.f,0.f,0.f,0.f,0.f};
#pragma unroll
    for (int s = 0; s < 16; ++s) {
      half8 Ah = wt[cur][s * 64 + lane];
      acc = __builtin_amdgcn_mfma_f32_32x32x16_f16(Ah, eh[s], acc, 0, 0, 0);
    }
    int nb = cur ^ 1;
    if (pf) {
#pragma unroll
      for (int r = 0; r < 8; ++r) wt[nb][r * 128 + tid] = g[r];
    }
    // epilogue: d = ||w||^2 - 2 S ; top2 update (first-min tie-break)
    // C/D: token = lane&31, cluster-row = (reg&3) + 8*(reg>>2) + 4*khalf
#pragma unroll
    for (int q = 0; q < 4; ++q) {
      float4 w4 = *(const float4*)(wn + t * 32 + q * 8 + khalf * 4);
      float wv[4] = {w4.x, w4.y, w4.z, w4.w};
#pragma unroll
      for (int rr = 0; rr < 4; ++rr) {
        float d = wv[rr] - 2.0f * acc[q * 4 + rr];
        int c = t * 32 + rr + 8 * q + 4 * khalf;
        bool lt = (d < v1) || (d == v1 && c < i1);
        v2 = fminf(v2, lt ? v1 : d);
        if (lt) { v1 = d; i1 = c; }
      }
    }
    cur = nb;
    // layer finalize: merge lane/lane+32, flag near-ties, write winning rows
    if (t == 68 || t == 74 || t == 75) {
      int L, basePad; const float* WL;
      if (t == 68)      { L = 0; basePad = 0;    WL = w0; }
      else if (t == 74) { L = 1; basePad = 2208; WL = w1; }
      else              { L = 2; basePad = 2400; WL = w2; }
      float a1 = v1; int b1 = i1; float a2 = v2;
      {
        float o1 = __shfl_xor(a1, 32, 64);
        int   oi = __shfl_xor(b1, 32, 64);
        float o2 = __shfl_xor(a2, 32, 64);
        bool take = (o1 < a1) || (o1 == a1 && oi < b1);
        float loser = take ? a1 : o1;
        if (take) { a1 = o1; b1 = oi; }
        a2 = fminf(loser, fminf(a2, o2));
      }
      int li = b1 - basePad;
      if (khalf == 0) {
        if (a2 - a1 < TAU) {
          int token = tokbase + col;
          int pos = atomicAdd((int*)(ws + WS_FLAGCNT), 1);
          if (pos < WS_NFLAGS) ((int*)(ws + WS_FLAGS))[pos] = (L << 16) | token;
        }
      }
#pragma unroll 1
      for (int r = 0; r < 32; ++r) {
        int ir = __shfl(li, r, 64);
        const f32x4* src = (const f32x4*)(WL + (size_t)ir * DIM);
        f32x4* dst = (f32x4*)(out + ((size_t)(L * N_TOK + tokbase + r)) * DIM);
        __builtin_nontemporal_store(src[lane], &dst[lane]);
      }
      v1 = __builtin_inff(); v2 = __builtin_inff(); i1 = 0x7fffffff;
    }
  }
}

// ------- refine: exact fp64 rescan, 16-lane cluster groups, coalesced --------
__global__ __launch_bounds__(256) void refine_kernel(
    const float* __restrict__ E, const float* __restrict__ w0,
    const float* __restrict__ w1, const float* __restrict__ w2,
    float* __restrict__ out, unsigned char* __restrict__ ws) {
  __shared__ float esh[DIM];
  __shared__ double wbv[4];
  __shared__ int    wbi[4];
  __shared__ int    sbi;
  const int tid  = threadIdx.x;
  const int lane = tid & 63;
  const int wave = tid >> 6;
  const int g    = tid >> 4;    // 0..15 cluster group
  const int sl   = tid & 15;    // sub-lane within group
  int cnt = *(const int*)(ws + WS_FLAGCNT);
  if (cnt > WS_NFLAGS) cnt = WS_NFLAGS;
  const int* flags = (const int*)(ws + WS_FLAGS);
  for (int f = blockIdx.x; f < cnt; f += gridDim.x) {
    int lin = flags[f];
    int L = lin >> 16, tok = lin & 0xffff;
    const float* WL; int csize;
    if (L == 0)      { WL = w0; csize = 2197; }
    else if (L == 1) { WL = w1; csize = 169; }
    else             { WL = w2; csize = 13; }
    __syncthreads();                         // protect esh/wbv reuse
    esh[tid] = E[(size_t)tok * DIM + tid];   // tid < 256 == DIM
    __syncthreads();
    double best = 1e300; int bi = 0x7fffffff;
    const float4* er = (const float4*)esh;
    for (int c = g; c < csize; c += 16) {
      const float4* row = (const float4*)(WL + (size_t)c * DIM);
      double s0 = 0.0, s1 = 0.0, s2 = 0.0, s3 = 0.0;
#pragma unroll
      for (int p = 0; p < 4; ++p) {
        float4 wv = row[p * 16 + sl];
        float4 ev = er [p * 16 + sl];
        double d0 = (double)wv.x - (double)ev.x;
        double d1 = (double)wv.y - (double)ev.y;
        double d2 = (double)wv.z - (double)ev.z;
        double d3 = (double)wv.w - (double)ev.w;
        s0 += d0 * d0; s1 += d1 * d1; s2 += d2 * d2; s3 += d3 * d3;
      }
      double s = (s0 + s1) + (s2 + s3);
      s += __shfl_xor(s, 1, 64);
      s += __shfl_xor(s, 2, 64);
      s += __shfl_xor(s, 4, 64);
      s += __shfl_xor(s, 8, 64);
      if (s < best || (s == best && c < bi)) { best = s; bi = c; }
    }
    // merge 4 groups within the wave
    {
      double ob = __shfl_xor(best, 16, 64); int oi = __shfl_xor(bi, 16, 64);
      if (ob < best || (ob == best && oi < bi)) { best = ob; bi = oi; }
      ob = __shfl_xor(best, 32, 64); oi = __shfl_xor(bi, 32, 64);
      if (ob < best || (ob == best && oi < bi)) { best = ob; bi = oi; }
    }
    if (lane == 0) { wbv[wave] = best; wbi[wave] = bi; }
    __syncthreads();
    if (tid == 0) {
      double b = wbv[0]; int x = wbi[0];
#pragma unroll
      for (int w = 1; w < 4; ++w)
        if (wbv[w] < b || (wbv[w] == b && wbi[w] < x)) { b = wbv[w]; x = wbi[w]; }
      sbi = x;
    }
    __syncthreads();
    int bidx = sbi;
    out[((size_t)(L * N_TOK + tok)) * DIM + tid] = WL[(size_t)bidx * DIM + tid];
  }
}

extern "C" void kernel_launch(void* const* d_in, const int* in_sizes, int n_in,
                              void* d_out, int out_size, void* d_ws, size_t ws_size,
                              hipStream_t stream) {
  const float* E  = (const float*)d_in[0];
  const float* w0 = (const float*)d_in[1];
  const float* w1 = (const float*)d_in[2];
  const float* w2 = (const float*)d_in[3];
  float* out = (float*)d_out;
  unsigned char* ws = (unsigned char*)d_ws;

  hipLaunchKernelGGL(prep_kernel,   dim3(NT),   dim3(256), 0, stream, w0, w1, w2, ws);
  hipLaunchKernelGGL(argmin_kernel, dim3(1024), dim3(128), 0, stream, E, w0, w1, w2, out, ws);
  hipLaunchKernelGGL(refine_kernel, dim3(1024), dim3(256), 0, stream, E, w0, w1, w2, out, ws);
}